// Round 1
// baseline (998.659 us; speedup 1.0000x reference)
//
#include <hip/hip_runtime.h>
#include <math.h>

#define EPS 1e-5f
#define N_GRAPHS 128

__device__ __forceinline__ float sigmoidf_(float x) {
    return __fdividef(1.0f, 1.0f + __expf(-x));
}

// ---------------------------------------------------------------------------
// Projection kernel: for a tile of 64 nodes, compute k,q,v,s = x@W + b for the
// four weight matrices. Writes:
//   B[n*64+o]        = k
//   A[n*128 + 2o]    = q   (q,v interleaved for the edge gather)
//   A[n*128 + 2o+1]  = v
//   AGG[n*64+o]      = s   (x@Ws + cb, the aggregation init value)
// Block: 256 threads = 4 waves; lane = node-in-tile, wave = 16-output group.
// W reads are wave-uniform -> scalar loads (one SGPR operand per v_fma).
// ---------------------------------------------------------------------------
template <int IN>
__global__ __launch_bounds__(256) void proj_kernel(
    const float* __restrict__ x,
    const float* __restrict__ Wk, const float* __restrict__ bk,
    const float* __restrict__ Wq, const float* __restrict__ bq,
    const float* __restrict__ Wv, const float* __restrict__ bv,
    const float* __restrict__ Ws, const float* __restrict__ cb,
    float* __restrict__ A, float* __restrict__ B, float* __restrict__ AGG,
    int N)
{
    __shared__ float xs[64 * (IN + 1)];   // +1 pad: (lane+k)%32 banks, 2-way free
    const int tid = threadIdx.x;
    const int n0 = blockIdx.x * 64;

    for (int idx = tid; idx < 64 * IN; idx += 256) {
        int r = idx / IN, c = idx - r * IN;
        int n = n0 + r;
        xs[r * (IN + 1) + c] = (n < N) ? x[(size_t)n * IN + c] : 0.0f;
    }
    __syncthreads();

    const int lane = tid & 63;
    const int wave = __builtin_amdgcn_readfirstlane(tid >> 6);  // 0..3
    const int node = n0 + lane;
    const int o0 = wave * 16;

    const float* Wlist[4] = {Wk, Wq, Wv, Ws};
    const float* blist[4] = {bk, bq, bv, cb};

#pragma unroll
    for (int p = 0; p < 4; ++p) {
        const float* __restrict__ W = Wlist[p];
        float acc[16];
#pragma unroll
        for (int j = 0; j < 16; ++j) acc[j] = blist[p][o0 + j];

        for (int k = 0; k < IN; ++k) {
            float xv = xs[lane * (IN + 1) + k];
            const float* wr = W + k * 64 + o0;   // scalar address
#pragma unroll
            for (int j = 0; j < 16; ++j) acc[j] = fmaf(xv, wr[j], acc[j]);
        }
        if (node < N) {
#pragma unroll
            for (int j = 0; j < 16; ++j) {
                int o = o0 + j;
                float val = acc[j];
                if (p == 0)      B[(size_t)node * 64 + o] = val;
                else if (p == 1) A[(size_t)node * 128 + 2 * o] = val;
                else if (p == 2) A[(size_t)node * 128 + 2 * o + 1] = val;
                else             AGG[(size_t)node * 64 + o] = val;
            }
        }
    }
}

// ---------------------------------------------------------------------------
// Edge kernel: one wave per edge iteration; lane = channel (64 channels).
//   msg = sigmoid(k[dst] + q[src]) * v[src];  AGG[dst] += msg (atomic)
// ---------------------------------------------------------------------------
__global__ __launch_bounds__(256) void edge_kernel(
    const int* __restrict__ ei, const float* __restrict__ A,
    const float* __restrict__ B, float* __restrict__ AGG, int E)
{
    const int lane = threadIdx.x & 63;
    const int wv = __builtin_amdgcn_readfirstlane(
        (int)((blockIdx.x * blockDim.x + threadIdx.x) >> 6));
    const int nw = (gridDim.x * blockDim.x) >> 6;

    for (int e = wv; e < E; e += nw) {
        int src = ei[e];          // scalar loads (e is SGPR)
        int dst = ei[E + e];
        float2 qv = *(const float2*)(A + (size_t)src * 128 + 2 * lane);
        float k = B[(size_t)dst * 64 + lane];
        float msg = sigmoidf_(k + qv.x) * qv.y;
        atomicAdd(&AGG[(size_t)dst * 64 + lane], msg);
    }
}

// ---------------------------------------------------------------------------
// Sigmoid + per-channel sum/sumsq (for BN). Y updated in place.
// stats[0:64] = sum, stats[64:128] = sumsq.
// ---------------------------------------------------------------------------
__global__ __launch_bounds__(256) void sig_stats_kernel(
    float* __restrict__ Y, float* __restrict__ stats, int N)
{
    const int lane = threadIdx.x & 63;
    const int w = threadIdx.x >> 6;
    const int gw = (int)((blockIdx.x * blockDim.x + threadIdx.x) >> 6);
    const int nw = (gridDim.x * blockDim.x) >> 6;

    float s1 = 0.0f, s2 = 0.0f;
    for (int n = gw; n < N; n += nw) {
        float v = Y[(size_t)n * 64 + lane];
        float y = sigmoidf_(v);
        Y[(size_t)n * 64 + lane] = y;
        s1 += y;
        s2 += y * y;
    }
    __shared__ float ls1[4][64], ls2[4][64];
    ls1[w][lane] = s1;
    ls2[w][lane] = s2;
    __syncthreads();
    if (threadIdx.x < 64) {
        float a = ls1[0][lane] + ls1[1][lane] + ls1[2][lane] + ls1[3][lane];
        float b = ls2[0][lane] + ls2[1][lane] + ls2[2][lane] + ls2[3][lane];
        atomicAdd(&stats[lane], a);
        atomicAdd(&stats[64 + lane], b);
    }
}

// ---------------------------------------------------------------------------
// BN-normalize + per-graph readout sum. One wave per block; contiguous node
// chunk; batch is sorted so run-length accumulate in registers, flush one
// atomic per (graph transition, channel).
// ---------------------------------------------------------------------------
__global__ __launch_bounds__(64) void norm_kernel(
    const float* __restrict__ Y, const float* __restrict__ stats,
    const float* __restrict__ g, const float* __restrict__ be,
    const int* __restrict__ batch,
    float* __restrict__ Xn, float* __restrict__ gsum,
    int N, float invN)
{
    const int lane = threadIdx.x;
    const int chunk = (N + gridDim.x - 1) / gridDim.x;
    const int nA = blockIdx.x * chunk;
    const int nB = min(N, nA + chunk);

    float m = stats[lane] * invN;
    float var = stats[64 + lane] * invN - m * m;
    float rs = rsqrtf(var + EPS) * g[lane];
    float bb = be[lane];

    float acc = 0.0f;
    int cur = -1;
    for (int n = nA; n < nB; ++n) {
        int gi = __builtin_amdgcn_readfirstlane(batch[n]);
        float y = Y[(size_t)n * 64 + lane];
        float v = (y - m) * rs + bb;
        Xn[(size_t)n * 64 + lane] = v;
        if (gi != cur) {
            if (cur >= 0) atomicAdd(&gsum[cur * 64 + lane], acc);
            acc = 0.0f;
            cur = gi;
        }
        acc += v;
    }
    if (cur >= 0) atomicAdd(&gsum[cur * 64 + lane], acc);
}

// ---------------------------------------------------------------------------
// Node counts per graph (run-length + atomic flush).
// ---------------------------------------------------------------------------
__global__ __launch_bounds__(256) void counts_kernel(
    const int* __restrict__ batch, float* __restrict__ counts, int N)
{
    const int t = blockIdx.x * blockDim.x + threadIdx.x;
    const int T = gridDim.x * blockDim.x;
    const int chunk = (N + T - 1) / T;
    const int a = t * chunk;
    const int b = min(N, a + chunk);
    int cur = -1;
    float c = 0.0f;
    for (int n = a; n < b; ++n) {
        int gi = batch[n];
        if (gi != cur) {
            if (cur >= 0) atomicAdd(&counts[cur], c);
            cur = gi;
            c = 0.0f;
        }
        c += 1.0f;
    }
    if (cur >= 0) atomicAdd(&counts[cur], c);
}

// ---------------------------------------------------------------------------
// Head 1: feat = [mean0 | mean1 | sum0 | sum1] (256), t0 = sigmoid(feat@Wh0+bh0)
// + stats for BN over 128 graphs. One block per graph, 128 threads = outputs.
// ---------------------------------------------------------------------------
__global__ __launch_bounds__(128) void head1_kernel(
    const float* __restrict__ gsum0, const float* __restrict__ gsum1,
    const float* __restrict__ counts,
    const float* __restrict__ Wh0, const float* __restrict__ bh0,
    float* __restrict__ t0, float* __restrict__ hstat0)
{
    const int gr = blockIdx.x;   // graph
    const int o = threadIdx.x;   // output channel (128)
    __shared__ float feat[256];
    float cnt = fmaxf(counts[gr], 1.0f);
    float inv = __fdividef(1.0f, cnt);
    if (o < 64) {
        float s = gsum0[gr * 64 + o];
        feat[o] = s * inv;
        feat[128 + o] = s;
    } else {
        int c = o - 64;
        float s = gsum1[gr * 64 + c];
        feat[64 + c] = s * inv;
        feat[192 + c] = s;
    }
    __syncthreads();
    float acc = bh0[o];
    for (int j = 0; j < 256; ++j) acc = fmaf(feat[j], Wh0[j * 128 + o], acc);
    float y = sigmoidf_(acc);
    t0[gr * 128 + o] = y;
    atomicAdd(&hstat0[o], y);
    atomicAdd(&hstat0[128 + o], y * y);
}

// ---------------------------------------------------------------------------
// Head 2: bn0 = BN(t0); t1 = sigmoid(bn0@Wh1+bh1) + stats.
// ---------------------------------------------------------------------------
__global__ __launch_bounds__(64) void head2_kernel(
    const float* __restrict__ t0, const float* __restrict__ hstat0,
    const float* __restrict__ gh0, const float* __restrict__ beh0,
    const float* __restrict__ Wh1, const float* __restrict__ bh1,
    float* __restrict__ t1, float* __restrict__ hstat1)
{
    const int gr = blockIdx.x;
    const int o = threadIdx.x;   // 64
    __shared__ float bn0[128];
    const float invG = 1.0f / (float)N_GRAPHS;
    for (int j = o; j < 128; j += 64) {
        float m = hstat0[j] * invG;
        float v = hstat0[128 + j] * invG - m * m;
        bn0[j] = (t0[gr * 128 + j] - m) * rsqrtf(v + EPS) * gh0[j] + beh0[j];
    }
    __syncthreads();
    float acc = bh1[o];
    for (int j = 0; j < 128; ++j) acc = fmaf(bn0[j], Wh1[j * 64 + o], acc);
    float y = sigmoidf_(acc);
    t1[gr * 64 + o] = y;
    atomicAdd(&hstat1[o], y);
    atomicAdd(&hstat1[64 + o], y * y);
}

// ---------------------------------------------------------------------------
// Head 3: bn1 = BN(t1); out = bn1@Wc + bc  -> [128,2]
// ---------------------------------------------------------------------------
__global__ __launch_bounds__(64) void head3_kernel(
    const float* __restrict__ t1, const float* __restrict__ hstat1,
    const float* __restrict__ gh1, const float* __restrict__ beh1,
    const float* __restrict__ Wc, const float* __restrict__ bc,
    float* __restrict__ out)
{
    const int gr = blockIdx.x;
    const int o = threadIdx.x;   // 64
    const float invG = 1.0f / (float)N_GRAPHS;
    float m = hstat1[o] * invG;
    float v = hstat1[64 + o] * invG - m * m;
    float b = (t1[gr * 64 + o] - m) * rsqrtf(v + EPS) * gh1[o] + beh1[o];
    float p0 = b * Wc[o * 2];
    float p1 = b * Wc[o * 2 + 1];
#pragma unroll
    for (int off = 32; off > 0; off >>= 1) {
        p0 += __shfl_down(p0, off);
        p1 += __shfl_down(p1, off);
    }
    if (o == 0) {
        out[gr * 2] = p0 + bc[0];
        out[gr * 2 + 1] = p1 + bc[1];
    }
}

// ---------------------------------------------------------------------------
extern "C" void kernel_launch(void* const* d_in, const int* in_sizes, int n_in,
                              void* d_out, int out_size, void* d_ws, size_t ws_size,
                              hipStream_t stream)
{
    const float* x     = (const float*)d_in[0];
    const int*   ei    = (const int*)d_in[1];
    const int*   batch = (const int*)d_in[2];
    const int N = in_sizes[2];
    const int E = in_sizes[1] / 2;

    const float *Wk0 = (const float*)d_in[3],  *bk0 = (const float*)d_in[4];
    const float *Wq0 = (const float*)d_in[5],  *bq0 = (const float*)d_in[6];
    const float *Wv0 = (const float*)d_in[7],  *bv0 = (const float*)d_in[8];
    const float *Ws0 = (const float*)d_in[9],  *cb0 = (const float*)d_in[10];
    const float *g0  = (const float*)d_in[11], *be0 = (const float*)d_in[12];
    const float *Wk1 = (const float*)d_in[13], *bk1 = (const float*)d_in[14];
    const float *Wq1 = (const float*)d_in[15], *bq1 = (const float*)d_in[16];
    const float *Wv1 = (const float*)d_in[17], *bv1 = (const float*)d_in[18];
    const float *Ws1 = (const float*)d_in[19], *cb1 = (const float*)d_in[20];
    const float *g1  = (const float*)d_in[21], *be1 = (const float*)d_in[22];
    const float *Wh0 = (const float*)d_in[23], *bh0 = (const float*)d_in[24];
    const float *gh0 = (const float*)d_in[25], *beh0 = (const float*)d_in[26];
    const float *Wh1 = (const float*)d_in[27], *bh1 = (const float*)d_in[28];
    const float *gh1 = (const float*)d_in[29], *beh1 = (const float*)d_in[30];
    const float *Wc  = (const float*)d_in[31], *bc  = (const float*)d_in[32];

    float* ws = (float*)d_ws;
    float* A    = ws;                     // N*128  (q,v interleaved)
    float* B    = A + (size_t)N * 128;    // N*64   (k)
    float* AGG  = B + (size_t)N * 64;     // N*64   (agg -> sigmoid output)
    float* X1   = AGG + (size_t)N * 64;   // N*64   (layer-1 input)
    float* zb   = X1 + (size_t)N * 64;    // zeroed scratch begins here
    float* gsum0  = zb;                   // 128*64
    float* gsum1  = gsum0 + 128 * 64;     // 128*64
    float* counts = gsum1 + 128 * 64;     // 128
    float* stats0 = counts + 128;         // 128
    float* stats1 = stats0 + 128;         // 128
    float* hstat0 = stats1 + 128;         // 256
    float* hstat1 = hstat0 + 256;         // 128
    size_t zbytes = (size_t)(128 * 64 * 2 + 128 * 3 + 256 + 128) * sizeof(float);
    float* t0 = hstat1 + 128;             // 128*128
    float* t1 = t0 + 128 * 128;           // 128*64

    hipMemsetAsync(zb, 0, zbytes, stream);

    const int projBlocks = (N + 63) / 64;

    // ---- layer 0 ----
    proj_kernel<128><<<projBlocks, 256, 0, stream>>>(
        x, Wk0, bk0, Wq0, bq0, Wv0, bv0, Ws0, cb0, A, B, AGG, N);
    edge_kernel<<<2048, 256, 0, stream>>>(ei, A, B, AGG, E);
    sig_stats_kernel<<<256, 256, 0, stream>>>(AGG, stats0, N);
    counts_kernel<<<16, 256, 0, stream>>>(batch, counts, N);
    norm_kernel<<<1024, 64, 0, stream>>>(AGG, stats0, g0, be0, batch,
                                         X1, gsum0, N, 1.0f / (float)N);

    // ---- layer 1 ----
    proj_kernel<64><<<projBlocks, 256, 0, stream>>>(
        X1, Wk1, bk1, Wq1, bq1, Wv1, bv1, Ws1, cb1, A, B, AGG, N);
    edge_kernel<<<2048, 256, 0, stream>>>(ei, A, B, AGG, E);
    sig_stats_kernel<<<256, 256, 0, stream>>>(AGG, stats1, N);
    norm_kernel<<<1024, 64, 0, stream>>>(AGG, stats1, g1, be1, batch,
                                         X1, gsum1, N, 1.0f / (float)N);

    // ---- head ----
    head1_kernel<<<128, 128, 0, stream>>>(gsum0, gsum1, counts, Wh0, bh0, t0, hstat0);
    head2_kernel<<<128, 64, 0, stream>>>(t0, hstat0, gh0, beh0, Wh1, bh1, t1, hstat1);
    head3_kernel<<<128, 64, 0, stream>>>(t1, hstat1, gh1, beh1, Wc, bc, (float*)d_out);
}